// Round 7
// baseline (165.914 us; speedup 1.0000x reference)
//
#include <hip/hip_runtime.h>
#include <stdint.h>

// ---- types ----
typedef __attribute__((ext_vector_type(4))) float   f4;
typedef __attribute__((ext_vector_type(8))) short   short8;   // 8 x bf16 (MFMA A/B frag)
typedef __attribute__((ext_vector_type(4))) float   floatx4;  // MFMA C/D frag
typedef __attribute__((ext_vector_type(4))) unsigned int u32x4;

#define LN2F 0.6931471805599453f

// Problem constants
#define BB 65536
#define SS 512
#define DD 100
// K padded to 128 (4 k-steps of 32 for mfma 16x16x32 bf16)

__device__ __forceinline__ unsigned short f2bf(float f) {
  union { float f; unsigned int u; } v; v.f = f;
  unsigned int u = v.u;
  u += 0x7fffu + ((u >> 16) & 1u);   // RNE
  return (unsigned short)(u >> 16);
}
__device__ __forceinline__ u32x4 pack8(f4 a, f4 b) {
  u32x4 r;
  r.x = (unsigned int)f2bf(a[0]) | ((unsigned int)f2bf(a[1]) << 16);
  r.y = (unsigned int)f2bf(a[2]) | ((unsigned int)f2bf(a[3]) << 16);
  r.z = (unsigned int)f2bf(b[0]) | ((unsigned int)f2bf(b[1]) << 16);
  r.w = (unsigned int)f2bf(b[2]) | ((unsigned int)f2bf(b[3]) << 16);
  return r;
}
__device__ __forceinline__ short8 pack8s(f4 a, f4 b) {
  return __builtin_bit_cast(short8, pack8(a, b));
}
// numerically stable softplus(x) = log(1+e^x)
__device__ __forceinline__ float softplus_full(float x) {
  return fmaxf(x, 0.f) + log1pf(expf(-fabsf(x)));
}
__device__ __forceinline__ float dot4(f4 a, f4 b) {
  return a[0]*b[0] + a[1]*b[1] + a[2]*b[2] + a[3]*b[3];
}

// ---------------------------------------------------------------------------
// Kernel 1: gather + convert neg rows into MFMA B-fragment tiled layout in ws.
// Unit index = (sgroup*4 + kstep)*64 + (s&15) + 16*kquad; k>=100 zeroed
// (this zeroing is what makes junk A-fragment lanes harmless in keg_main).
// Also zero-inits out[0].
// ---------------------------------------------------------------------------
__global__ __launch_bounds__(256) void negprep_k(
    const float* __restrict__ tail_table, const int* __restrict__ neg_idx,
    u32x4* __restrict__ nws, float* __restrict__ out) {
  if (blockIdx.x == 0 && threadIdx.x == 0) out[0] = 0.f;
  int tid = blockIdx.x * 256 + threadIdx.x;          // 32 blocks -> 8192 threads
  int s = tid >> 4, kg = tid & 15, k0 = kg * 8;      // 16 threads per s-row
  int nrow = neg_idx[s];
  const float* np = tail_table + (size_t)nrow * DD;  // rows 400B, 16B aligned
  // unconditional loads stay inside the table (max base (TV-1)*100 + 127 < (TV+1)*100)
  f4 a = *(const f4*)(np + k0);
  f4 b = *(const f4*)(np + k0 + 4);
  if (kg > 12)  a = (f4){0.f,0.f,0.f,0.f};
  if (kg >= 12) b = (f4){0.f,0.f,0.f,0.f};
  nws[((s >> 4) * 4 + (kg >> 2)) * 64 + (s & 15) + 16 * (kg & 3)] = pack8(a, b);
}

// ---------------------------------------------------------------------------
// Kernel 2: fused main, BARRIER-FREE decomposition. 1024 blocks x 256 thr;
// each of the 4 waves independently owns 16 b-rows x all 512 s.
// Lane (r=lane&15, q=lane>>4) gathers its MFMA A-fragment DIRECTLY from the
// head row (k = q*8 + 32*ks + 0..7): no LDS staging, no transpose barrier.
// Tail row gathered alongside for the fused fp32 pos-loss (completes under
// the MFMA loop). Junk k in [100,128) of A is multiplied by zeroed B. Waves
// de-phase naturally, overlapping gather latency with MFMA across the CU.
// ---------------------------------------------------------------------------
__global__ __launch_bounds__(256, 4) void keg_main(
    const float* __restrict__ head_table, const float* __restrict__ tail_table,
    const float* __restrict__ rel_vec,   const float* __restrict__ rel_bias,
    const int* __restrict__ head_idx,    const int* __restrict__ tail_idx,
    const u32x4* __restrict__ nws,       float* __restrict__ out) {
  __shared__ float red[4];
  const int t = threadIdx.x, w = t >> 6, lane = t & 63;
  const int r = lane & 15, q = lane >> 4;
  const int R = blockIdx.x * 64 + w * 16 + r;   // this lane's b-row

  // ---- index + bias loads (16 distinct addrs, 4-lane broadcast) ----
  int hrow = head_idx[R], trow = tail_idx[R];
  const float* hp = head_table + (size_t)hrow * DD;
  const float* tp = tail_table + (size_t)trow * DD;
  float mybias = rel_bias[trow];

  // ---- batched gather: 16 unconditional dwordx4, all issued up front ----
  // max offset = 120+7 = 127 floats past row base: in bounds for both tables.
  f4 h0[4], h1[4], t0[4], t1[4];
  #pragma unroll
  for (int ks = 0; ks < 4; ++ks) {
    int kk = q * 8 + 32 * ks;
    h0[ks] = *(const f4*)(hp + kk);
    h1[ks] = *(const f4*)(hp + kk + 4);
    t0[ks] = *(const f4*)(tp + kk);
    t1[ks] = *(const f4*)(tp + kk + 4);
  }
  // rel chunks (rel_vec has exactly 100 floats -> mask OOB; L1 broadcast)
  f4 r0[4], r1[4];
  #pragma unroll
  for (int ks = 0; ks < 4; ++ks) {
    int kk = q * 8 + 32 * ks;
    f4 z = {0.f,0.f,0.f,0.f};
    r0[ks] = (kk     < 97) ? *(const f4*)(rel_vec + kk)     : z;  // kk<=96 valid
    r1[ks] = (kk + 4 < 97) ? *(const f4*)(rel_vec + kk + 4) : z;
  }

  // ---- A-fragments: ex = h + rel (fp32), RNE -> bf16 ----
  short8 afr[4];
  f4 e0[4], e1[4];
  #pragma unroll
  for (int ks = 0; ks < 4; ++ks) {
    e0[ks] = h0[ks] + r0[ks];
    e1[ks] = h1[ks] + r1[ks];
    afr[ks] = pack8s(e0[ks], e1[ks]);  // junk k>=100 harmless: B is zero there
  }

  // ---- fused pos loss (fp32): mask k>=100 (only ks=3 region) ----
  float d = 0.f;
  #pragma unroll
  for (int ks = 0; ks < 3; ++ks)
    d += dot4(e0[ks], t0[ks]) + dot4(e1[ks], t1[ks]);
  if (q == 0) d += dot4(e0[3], t0[3]);        // k 96..99; rest of ks=3 is junk
  d += __shfl_xor(d, 16);
  d += __shfl_xor(d, 32);                     // all 4 quads now hold full dot
  float pos_acc = 0.f;
  if (q == 0) pos_acc = softplus_full(-(d + mybias));   // -log_sigmoid(pos)

  // ---- bias for this lane's 4 C-rows (m = q*4 + r2) via shuffle ----
  float br[4];
  #pragma unroll
  for (int r2 = 0; r2 < 4; ++r2) br[r2] = __shfl(mybias, q * 4 + r2);

  // ---- neg matmul: 32 s-groups x 4 MFMA, branchless moment epilogue ----
  const short8* nf = (const short8*)nws;
  float s1 = 0.f, s2 = 0.f, amax = 0.f;
  #pragma unroll 2
  for (int ng = 0; ng < 32; ++ng) {
    short8 bfr[4];
    #pragma unroll
    for (int ks = 0; ks < 4; ++ks)
      bfr[ks] = nf[(ng * 4 + ks) * 64 + lane];   // coalesced 1KB, L1/L2-hot
    floatx4 acc;
    acc[0] = br[0]; acc[1] = br[1]; acc[2] = br[2]; acc[3] = br[3];
    #pragma unroll
    for (int ks = 0; ks < 4; ++ks)
      acc = __builtin_amdgcn_mfma_f32_16x16x32_bf16(afr[ks], bfr[ks], acc, 0, 0, 0);
    #pragma unroll
    for (int r2 = 0; r2 < 4; ++r2) {
      float x = acc[r2];
      s1 += x;
      s2 = fmaf(x, x, s2);
      amax = fmaxf(amax, fabsf(x));              // fabs = input modifier
    }
  }
  // deg-2 Taylor softplus sum over this lane's 128 logits (|x|<0.03 -> err<5e-9)
  float nacc = fmaf(s1, 0.5f, fmaf(s2, 0.125f, 128.f * LN2F));
  if (__ballot(amax < 0.03f) != ~0ULL) {         // cold exact path (inline)
    nacc = 0.f;
    for (int ng = 0; ng < 32; ++ng) {
      short8 bfr[4];
      #pragma unroll
      for (int ks = 0; ks < 4; ++ks)
        bfr[ks] = nf[(ng * 4 + ks) * 64 + lane];
      floatx4 acc;
      acc[0] = br[0]; acc[1] = br[1]; acc[2] = br[2]; acc[3] = br[3];
      #pragma unroll
      for (int ks = 0; ks < 4; ++ks)
        acc = __builtin_amdgcn_mfma_f32_16x16x32_bf16(afr[ks], bfr[ks], acc, 0, 0, 0);
      #pragma unroll
      for (int r2 = 0; r2 < 4; ++r2)
        nacc += softplus_full(acc[r2]);
    }
  }

  // ---- block reduce -> atomic accumulate (exact pow2 1/BB scale) ----
  float tot = nacc + pos_acc;
  #pragma unroll
  for (int off = 32; off; off >>= 1) tot += __shfl_down(tot, off);
  if (lane == 0) red[w] = tot;
  __syncthreads();
  if (t == 0)
    atomicAdd(out, (red[0] + red[1] + red[2] + red[3]) * (1.0f / (float)BB));
}

extern "C" void kernel_launch(void* const* d_in, const int* in_sizes, int n_in,
                              void* d_out, int out_size, void* d_ws, size_t ws_size,
                              hipStream_t stream) {
  const float* head_table = (const float*)d_in[0];
  const float* tail_table = (const float*)d_in[1];
  const float* rel_vec    = (const float*)d_in[2];
  const float* rel_bias   = (const float*)d_in[3];
  const int*   head_idx   = (const int*)d_in[4];
  const int*   tail_idx   = (const int*)d_in[5];
  const int*   neg_idx    = (const int*)d_in[6];
  float* out = (float*)d_out;

  u32x4* nws = (u32x4*)d_ws;                 // 512 x 128 bf16 = 131072 B

  negprep_k<<<32, 256, 0, stream>>>(tail_table, neg_idx, nws, out);
  keg_main<<<1024, 256, 0, stream>>>(head_table, tail_table, rel_vec, rel_bias,
                                     head_idx, tail_idx, (const u32x4*)nws, out);
}

// Round 8
// 165.498 us; speedup vs baseline: 1.0025x; 1.0025x over previous
//
#include <hip/hip_runtime.h>
#include <stdint.h>

// ---- types ----
typedef __attribute__((ext_vector_type(4))) float   f4;
typedef __attribute__((ext_vector_type(8))) short   short8;   // 8 x bf16 (MFMA A/B frag)
typedef __attribute__((ext_vector_type(4))) float   floatx4;  // MFMA C/D frag
typedef __attribute__((ext_vector_type(4))) unsigned int u32x4;

#define AS1 __attribute__((address_space(1)))
#define AS3 __attribute__((address_space(3)))
#define LN2F 0.6931471805599453f

// Problem constants
#define BB 65536
#define SS 512
#define DD 100
// K padded to 128 (4 k-steps of 32 for mfma 16x16x32 bf16)

__device__ __forceinline__ unsigned short f2bf(float f) {
  union { float f; unsigned int u; } v; v.f = f;
  unsigned int u = v.u;
  u += 0x7fffu + ((u >> 16) & 1u);   // RNE
  return (unsigned short)(u >> 16);
}
__device__ __forceinline__ u32x4 pack8(f4 a, f4 b) {
  u32x4 r;
  r.x = (unsigned int)f2bf(a[0]) | ((unsigned int)f2bf(a[1]) << 16);
  r.y = (unsigned int)f2bf(a[2]) | ((unsigned int)f2bf(a[3]) << 16);
  r.z = (unsigned int)f2bf(b[0]) | ((unsigned int)f2bf(b[1]) << 16);
  r.w = (unsigned int)f2bf(b[2]) | ((unsigned int)f2bf(b[3]) << 16);
  return r;
}
__device__ __forceinline__ short8 pack8s(f4 a, f4 b) {
  return __builtin_bit_cast(short8, pack8(a, b));
}
// numerically stable softplus(x) = log(1+e^x)
__device__ __forceinline__ float softplus_full(float x) {
  return fmaxf(x, 0.f) + log1pf(expf(-fabsf(x)));
}
__device__ __forceinline__ float dot4(f4 a, f4 b) {
  return a[0]*b[0] + a[1]*b[1] + a[2]*b[2] + a[3]*b[3];
}
// async 16B global->LDS (no data VGPRs consumed; dest = wave base + lane*16)
__device__ __forceinline__ void gl_lds16(const float* g, float* l) {
  __builtin_amdgcn_global_load_lds((AS1 const void*)g, (AS3 void*)l, 16, 0, 0);
}

// ---------------------------------------------------------------------------
// Kernel 1: gather + convert neg rows into MFMA B-fragment tiled layout in ws.
// Unit index = (sgroup*4 + kstep)*64 + (s&15) + 16*kquad; k>=100 zeroed
// (this zeroing is what makes junk A-fragment lanes harmless in keg_main).
// Also zero-inits out[0].
// ---------------------------------------------------------------------------
__global__ __launch_bounds__(256) void negprep_k(
    const float* __restrict__ tail_table, const int* __restrict__ neg_idx,
    u32x4* __restrict__ nws, float* __restrict__ out) {
  if (blockIdx.x == 0 && threadIdx.x == 0) out[0] = 0.f;
  int tid = blockIdx.x * 256 + threadIdx.x;          // 32 blocks -> 8192 threads
  int s = tid >> 4, kg = tid & 15, k0 = kg * 8;      // 16 threads per s-row
  int nrow = neg_idx[s];
  const float* np = tail_table + (size_t)nrow * DD;  // rows 400B, 16B aligned
  // unconditional loads stay inside the table (max base (TV-1)*100 + 127 < (TV+1)*100)
  f4 a = *(const f4*)(np + k0);
  f4 b = *(const f4*)(np + k0 + 4);
  if (kg > 12)  a = (f4){0.f,0.f,0.f,0.f};
  if (kg >= 12) b = (f4){0.f,0.f,0.f,0.f};
  nws[((s >> 4) * 4 + (kg >> 2)) * 64 + (s & 15) + 16 * (kg & 3)] = pack8(a, b);
}

// ---------------------------------------------------------------------------
// Kernel 2: fused main, barrier-free, ASYNC-GATHER edition.
// 1024 blocks x 256 thr; each of 4 waves independently owns 16 b-rows x 512 s.
// Head rows: 8x global_load_lds(16B) per thread into a per-wave-private 8KB
// LDS region (no data VGPRs -> all 8 genuinely outstanding; R7's VGPR=52
// proved plain loads get serialized by register reuse). Tail rows: 8 dwordx4
// in VGPRs, issued alongside. One s_waitcnt vmcnt(0) (wave-private region, no
// __syncthreads). Then A-frags from LDS, fused fp32 pos loss, MFMA neg loop.
// ---------------------------------------------------------------------------
__global__ __launch_bounds__(256, 4) void keg_main(
    const float* __restrict__ head_table, const float* __restrict__ tail_table,
    const float* __restrict__ rel_vec,   const float* __restrict__ rel_bias,
    const int* __restrict__ head_idx,    const int* __restrict__ tail_idx,
    const u32x4* __restrict__ nws,       float* __restrict__ out) {
  __shared__ float hstage[4 * 2048];   // 8KB per wave, wave-private
  __shared__ float red[4];
  const int t = threadIdx.x, w = t >> 6, lane = t & 63;
  const int r = lane & 15, q = lane >> 4;
  const int R = blockIdx.x * 64 + w * 16 + r;   // this lane's b-row

  // ---- index + bias loads (16 distinct addrs, 4-lane broadcast) ----
  int hrow = head_idx[R], trow = tail_idx[R];
  const float* hp = head_table + (size_t)hrow * DD;
  const float* tp = tail_table + (size_t)trow * DD;
  float mybias = rel_bias[trow];

  float* wstg = hstage + w * 2048;
  // ---- 8 async head gathers -> LDS (per-lane gptr; dest lane*16) ----
  // unconditional: offset <= 127 floats past row base stays inside table
  #pragma unroll
  for (int i = 0; i < 8; ++i) {
    int ks = i >> 1, half = i & 1;
    gl_lds16(hp + q * 8 + 32 * ks + 4 * half, wstg + i * 256 + lane * 4);
  }
  // ---- 8 tail gathers in VGPRs, issued while head loads are in flight ----
  f4 t0[4], t1[4];
  #pragma unroll
  for (int ks = 0; ks < 4; ++ks) {
    int kk = q * 8 + 32 * ks;
    t0[ks] = *(const f4*)(tp + kk);
    t1[ks] = *(const f4*)(tp + kk + 4);
  }
  // rel chunks (rel_vec has exactly 100 floats -> mask OOB; L1 broadcast)
  f4 r0[4], r1[4];
  #pragma unroll
  for (int ks = 0; ks < 4; ++ks) {
    int kk = q * 8 + 32 * ks;
    f4 z = {0.f,0.f,0.f,0.f};
    r0[ks] = (kk     < 97) ? *(const f4*)(rel_vec + kk)     : z;  // kk<=96 valid
    r1[ks] = (kk + 4 < 97) ? *(const f4*)(rel_vec + kk + 4) : z;
  }

  // ---- drain the async gathers (wave-private region: no barrier needed) ----
  __builtin_amdgcn_sched_barrier(0);
  __builtin_amdgcn_s_waitcnt(0x0f70);   // vmcnt(0), expcnt/lgkmcnt no-wait
  __builtin_amdgcn_sched_barrier(0);

  // ---- A-fragments: ex = h + rel (fp32), RNE -> bf16 ----
  short8 afr[4];
  f4 e0[4], e1[4];
  #pragma unroll
  for (int ks = 0; ks < 4; ++ks) {
    f4 h0 = *(const f4*)(wstg + (ks * 2 + 0) * 256 + lane * 4);
    f4 h1 = *(const f4*)(wstg + (ks * 2 + 1) * 256 + lane * 4);
    e0[ks] = h0 + r0[ks];
    e1[ks] = h1 + r1[ks];
    afr[ks] = pack8s(e0[ks], e1[ks]);  // junk k>=100 harmless: B is zero there
  }

  // ---- fused pos loss (fp32): mask k>=100 (only ks=3 region) ----
  float d = 0.f;
  #pragma unroll
  for (int ks = 0; ks < 3; ++ks)
    d += dot4(e0[ks], t0[ks]) + dot4(e1[ks], t1[ks]);
  if (q == 0) d += dot4(e0[3], t0[3]);        // k 96..99; rest of ks=3 is junk
  d += __shfl_xor(d, 16);
  d += __shfl_xor(d, 32);                     // all 4 quads now hold full dot
  float pos_acc = 0.f;
  if (q == 0) pos_acc = softplus_full(-(d + mybias));   // -log_sigmoid(pos)

  // ---- bias for this lane's 4 C-rows (m = q*4 + r2) via shuffle ----
  float br[4];
  #pragma unroll
  for (int r2 = 0; r2 < 4; ++r2) br[r2] = __shfl(mybias, q * 4 + r2);

  // ---- neg matmul: 32 s-groups x 4 MFMA, branchless moment epilogue ----
  const short8* nf = (const short8*)nws;
  float s1 = 0.f, s2 = 0.f, amax = 0.f;
  #pragma unroll 2
  for (int ng = 0; ng < 32; ++ng) {
    short8 bfr[4];
    #pragma unroll
    for (int ks = 0; ks < 4; ++ks)
      bfr[ks] = nf[(ng * 4 + ks) * 64 + lane];   // coalesced 1KB, L1/L2-hot
    floatx4 acc;
    acc[0] = br[0]; acc[1] = br[1]; acc[2] = br[2]; acc[3] = br[3];
    #pragma unroll
    for (int ks = 0; ks < 4; ++ks)
      acc = __builtin_amdgcn_mfma_f32_16x16x32_bf16(afr[ks], bfr[ks], acc, 0, 0, 0);
    #pragma unroll
    for (int r2 = 0; r2 < 4; ++r2) {
      float x = acc[r2];
      s1 += x;
      s2 = fmaf(x, x, s2);
      amax = fmaxf(amax, fabsf(x));              // fabs = input modifier
    }
  }
  // deg-2 Taylor softplus sum over this lane's 128 logits (|x|<0.03 -> err<5e-9)
  float nacc = fmaf(s1, 0.5f, fmaf(s2, 0.125f, 128.f * LN2F));
  if (__ballot(amax < 0.03f) != ~0ULL) {         // cold exact path (inline)
    nacc = 0.f;
    for (int ng = 0; ng < 32; ++ng) {
      short8 bfr[4];
      #pragma unroll
      for (int ks = 0; ks < 4; ++ks)
        bfr[ks] = nf[(ng * 4 + ks) * 64 + lane];
      floatx4 acc;
      acc[0] = br[0]; acc[1] = br[1]; acc[2] = br[2]; acc[3] = br[3];
      #pragma unroll
      for (int ks = 0; ks < 4; ++ks)
        acc = __builtin_amdgcn_mfma_f32_16x16x32_bf16(afr[ks], bfr[ks], acc, 0, 0, 0);
      #pragma unroll
      for (int r2 = 0; r2 < 4; ++r2)
        nacc += softplus_full(acc[r2]);
    }
  }

  // ---- block reduce -> atomic accumulate (exact pow2 1/BB scale) ----
  float tot = nacc + pos_acc;
  #pragma unroll
  for (int off = 32; off; off >>= 1) tot += __shfl_down(tot, off);
  if (lane == 0) red[w] = tot;
  __syncthreads();
  if (t == 0)
    atomicAdd(out, (red[0] + red[1] + red[2] + red[3]) * (1.0f / (float)BB));
}

extern "C" void kernel_launch(void* const* d_in, const int* in_sizes, int n_in,
                              void* d_out, int out_size, void* d_ws, size_t ws_size,
                              hipStream_t stream) {
  const float* head_table = (const float*)d_in[0];
  const float* tail_table = (const float*)d_in[1];
  const float* rel_vec    = (const float*)d_in[2];
  const float* rel_bias   = (const float*)d_in[3];
  const int*   head_idx   = (const int*)d_in[4];
  const int*   tail_idx   = (const int*)d_in[5];
  const int*   neg_idx    = (const int*)d_in[6];
  float* out = (float*)d_out;

  u32x4* nws = (u32x4*)d_ws;                 // 512 x 128 bf16 = 131072 B

  negprep_k<<<32, 256, 0, stream>>>(tail_table, neg_idx, nws, out);
  keg_main<<<1024, 256, 0, stream>>>(head_table, tail_table, rel_vec, rel_bias,
                                     head_idx, tail_idx, (const u32x4*)nws, out);
}